// Round 6
// baseline (871.744 us; speedup 1.0000x reference)
//
#include <hip/hip_runtime.h>

#define FDIM 128

typedef __attribute__((ext_vector_type(8))) short bf16x8;
typedef __attribute__((ext_vector_type(4))) float f32x4;
typedef __attribute__((ext_vector_type(2))) float f32x2;

// ---------------- helpers ----------------

__device__ __forceinline__ unsigned int cvt_bf16(float f) {
    unsigned int u = __float_as_uint(f);
    return (u + 0x7fffu + ((u >> 16) & 1u)) >> 16;   // RNE
}
__device__ __forceinline__ float bf16_lo(unsigned int w) { return __uint_as_float(w << 16); }
__device__ __forceinline__ float bf16_hi(unsigned int w) { return __uint_as_float(w & 0xffff0000u); }

// bf16 packed layout (GEMM in/out): row of 64 uints; uint u = (feat u, feat u+64).
// fp8 gather layout: row of 64 ushorts; ushort u = e4m3 pair (feat u, feat u+64),
// value = dis[row] * hw[row][feat]  (pre-scaled by source norm).

// ---------------- CSR build ----------------

__global__ void hist_kernel(const int* __restrict__ tgt, int* __restrict__ count, int ne) {
    int e = blockIdx.x * blockDim.x + threadIdx.x;
    if (e < ne) atomicAdd(&count[tgt[e]], 1);
}

// ---- 3-phase parallel scan: 2048 elems/block ----
__global__ __launch_bounds__(256) void scan1_kernel(const int* __restrict__ count,
                                                    float* __restrict__ dis,
                                                    int* __restrict__ tpre,
                                                    int* __restrict__ bsum, int n) {
    __shared__ int sm[256];
    int tid = threadIdx.x, blk = blockIdx.x;
    int base = blk * 2048 + tid * 8;
    int s = 0;
    #pragma unroll
    for (int q = 0; q < 8; q++) {
        int i = base + q;
        if (i < n) {
            int c = count[i];
            s += c;
            dis[i] = rsqrtf((float)(c + 1));   // +1 self-loop
        }
    }
    sm[tid] = s;
    __syncthreads();
    for (int off = 1; off < 256; off <<= 1) {
        int v = sm[tid];
        int u = (tid >= off) ? sm[tid - off] : 0;
        __syncthreads();
        sm[tid] = v + u;
        __syncthreads();
    }
    tpre[blk * 256 + tid] = (tid == 0) ? 0 : sm[tid - 1];
    if (tid == 255) bsum[blk] = sm[255];
}

__global__ __launch_bounds__(1024) void scan2_kernel(const int* __restrict__ bsum,
                                                     int* __restrict__ bpre,
                                                     int* __restrict__ rowptr,
                                                     float* __restrict__ pool,
                                                     int n, int nb) {
    __shared__ int sm[1024];
    int tid = threadIdx.x;
    if (tid < 384) pool[tid] = 0.f;
    sm[tid] = (tid < nb) ? bsum[tid] : 0;
    __syncthreads();
    for (int off = 1; off < 1024; off <<= 1) {
        int v = sm[tid];
        int u = (tid >= off) ? sm[tid - off] : 0;
        __syncthreads();
        sm[tid] = v + u;
        __syncthreads();
    }
    if (tid < nb) bpre[tid] = (tid == 0) ? 0 : sm[tid - 1];
    if (tid == nb - 1) rowptr[n] = sm[tid];
}

__global__ __launch_bounds__(256) void scan3_kernel(const int* __restrict__ count,
                                                    const int* __restrict__ tpre,
                                                    const int* __restrict__ bpre,
                                                    int* __restrict__ rowptr,
                                                    int* __restrict__ cursor, int n) {
    int tid = threadIdx.x, blk = blockIdx.x;
    int run = bpre[blk] + tpre[blk * 256 + tid];
    int base = blk * 2048 + tid * 8;
    #pragma unroll
    for (int q = 0; q < 8; q++) {
        int i = base + q;
        if (i < n) {
            rowptr[i] = run;
            cursor[i] = run;
            run += count[i];
        }
    }
}

// csr entry: just the src node (dis[src] is pre-folded into the fp8 rows)
__global__ void fill_kernel(const int* __restrict__ src, const int* __restrict__ tgt,
                            int* __restrict__ cursor, int* __restrict__ csrs, int ne) {
    int e = blockIdx.x * blockDim.x + threadIdx.x;
    if (e < ne) {
        int t = tgt[e];
        int s = src[e];
        int slot = atomicAdd(&cursor[t], 1);
        csrs[slot] = s;
    }
}

// ---------------- prep: fp32 -> packed bf16 (+ count zero) ----------------

__global__ void xprep_kernel(const float* __restrict__ x, unsigned* __restrict__ x16,
                             int* __restrict__ count, int n, int total) {
    int i = blockIdx.x * blockDim.x + threadIdx.x;      // total = n*64
    if (i < total) {
        int m = i >> 6, u = i & 63;
        float lo = x[(size_t)m * 128 + u];
        float hi = x[(size_t)m * 128 + u + 64];
        x16[i] = cvt_bf16(lo) | (cvt_bf16(hi) << 16);
        if (i < n) count[i] = 0;
    }
}

// weights packed + g8 zero-row init (row n of the fp8 buffer)
__global__ void wprep_kernel(const float* __restrict__ W1, const float* __restrict__ W2,
                             const float* __restrict__ W3,
                             unsigned* __restrict__ B1, unsigned* __restrict__ B2,
                             unsigned* __restrict__ B3,
                             unsigned short* __restrict__ g8, int n) {
    int i = blockIdx.x * blockDim.x + threadIdx.x;      // 3*8192 + 64
    if (i < 3 * 8192) {
        int w = i >> 13;
        int j = i & 8191;
        const float* W = (w == 0) ? W1 : (w == 1) ? W2 : W3;
        unsigned* B    = (w == 0) ? B1 : (w == 1) ? B2 : B3;
        int nn = j >> 6, u = j & 63;
        float lo = W[(size_t)u * 128 + nn];
        float hi = W[(size_t)(u + 64) * 128 + nn];
        B[j] = cvt_bf16(lo) | (cvt_bf16(hi) << 16);
    } else if (i < 3 * 8192 + 64) {
        g8[(size_t)n * 64 + (i - 3 * 8192)] = 0;        // zero row for padded gathers
    }
}

// ---------------- GEMM: g8[n][64u] = fp8(dis[m] * (A16 @ W)) (bf16 MFMA) --------

__global__ __launch_bounds__(256) void gemm_kernel(const unsigned* __restrict__ A16,
                                                   const unsigned* __restrict__ Bt16,
                                                   const float* __restrict__ dis,
                                                   unsigned short* __restrict__ g8, int n) {
    int tid  = threadIdx.x;
    int wave = tid >> 6, lane = tid & 63;
    int quad = lane >> 4, r16 = lane & 15;
    int m0 = (blockIdx.x * 4 + wave) * 16;
    if (m0 >= n) return;

    f32x4 acc[8] = {};

    #pragma unroll
    for (int ks = 0; ks < 4; ks++) {
        int m = m0 + r16;
        if (m >= n) m = n - 1;
        uint4 av = *(const uint4*)(A16 + (size_t)m * 64 + ks * 16 + quad * 4);
        bf16x8 af = *(bf16x8*)&av;
        #pragma unroll
        for (int t = 0; t < 8; t++) {
            int ncol = t * 16 + r16;
            uint4 bv = *(const uint4*)(Bt16 + (size_t)ncol * 64 + ks * 16 + quad * 4);
            bf16x8 bf = *(bf16x8*)&bv;
            acc[t] = __builtin_amdgcn_mfma_f32_16x16x32_bf16(af, bf, acc[t], 0, 0, 0);
        }
    }

    #pragma unroll
    for (int r = 0; r < 4; r++) {
        int row = m0 + quad * 4 + r;
        if (row < n) {
            float dr = dis[row];
            #pragma unroll
            for (int t = 0; t < 4; t++) {
                int p = __builtin_amdgcn_cvt_pk_fp8_f32(dr * acc[t][r], dr * acc[t + 4][r], 0, false);
                g8[(size_t)row * 64 + t * 16 + r16] = (unsigned short)(p & 0xffff);
            }
        }
    }
}

// ---------------- Aggregation: one node per wave, fp8 rows, dbuf gathers --------
// result[t] = relu( dis[t] * (sum_{s in N(t)} g[s] + g[t]) + b )

#define AGG_ISSUE(buf, jj)                                            \
    { _Pragma("unroll") for (int q = 0; q < 8; q++) {                 \
        int s = __shfl(sreg, (jj) * 8 + q);                           \
        buf[q] = g8[(size_t)(unsigned)s * 64u + lane]; } }

#define AGG_CONSUME(buf)                                              \
    { _Pragma("unroll") for (int q = 0; q < 8; q++) {                 \
        f32x2 f = __builtin_amdgcn_cvt_pk_f32_fp8((int)buf[q], false);\
        a0 += f.x; a1 += f.y; } }

__global__ __launch_bounds__(512) void agg_kernel(const unsigned short* __restrict__ g8,
                                                  const float* __restrict__ dis,
                                                  const int* __restrict__ rowptr,
                                                  const int* __restrict__ csrs,
                                                  const float* __restrict__ bias,
                                                  unsigned* __restrict__ out16,   // may be null
                                                  float* __restrict__ pool, int n) {
    __shared__ float lpool[128];
    int tid = threadIdx.x;
    if (tid < 128) lpool[tid] = 0.f;
    __syncthreads();

    int wave = tid >> 6, lane = tid & 63;
    int node = blockIdx.x * 8 + wave;
    bool ok = node < n;

    float a0 = 0.f, a1 = 0.f;
    float di = 0.f;
    int beg = 0, end = 0;
    if (ok) {
        di = dis[node];
        // self term (g[node] already contains dis[node]*hw[node])
        f32x2 sf = __builtin_amdgcn_cvt_pk_f32_fp8((int)g8[(size_t)(unsigned)node * 64u + lane], false);
        a0 = sf.x; a1 = sf.y;
        beg = rowptr[node];
        end = rowptr[node + 1];
    }

    for (int b = beg; b < end; b += 64) {
        int m = min(64, end - b);
        int sreg = (lane < m) ? csrs[b + lane] : n;   // pad -> zero row
        int nbg = (m + 7) >> 3;
        unsigned short gv0[8], gv1[8];
        AGG_ISSUE(gv0, 0)
        int j = 0;
        while (true) {
            if (j + 1 < nbg) AGG_ISSUE(gv1, j + 1)
            AGG_CONSUME(gv0)
            j++;
            if (j >= nbg) break;
            if (j + 1 < nbg) AGG_ISSUE(gv0, j + 1)
            AGG_CONSUME(gv1)
            j++;
            if (j >= nbg) break;
        }
    }

    float r0 = 0.f, r1 = 0.f;
    if (ok) {
        r0 = fmaxf(di * a0 + bias[lane], 0.f);
        r1 = fmaxf(di * a1 + bias[lane + 64], 0.f);
        if (out16) out16[(size_t)(unsigned)node * 64u + lane] = cvt_bf16(r0) | (cvt_bf16(r1) << 16);
    }
    atomicAdd(&lpool[lane],      r0);
    atomicAdd(&lpool[lane + 64], r1);
    __syncthreads();
    if (tid < 128) atomicAdd(&pool[tid], lpool[tid]);
}

// ---------------- MLP head (single block) ----------------

__global__ __launch_bounds__(128) void mlp_kernel(const float* __restrict__ pool,
                                                  const float* __restrict__ fw1, const float* __restrict__ fb1,
                                                  const float* __restrict__ fw2, const float* __restrict__ fb2,
                                                  const float* __restrict__ fw3, const float* __restrict__ fb3,
                                                  float* __restrict__ out) {
    __shared__ float h0[384];
    __shared__ float h1[128];
    __shared__ float h2[64];
    int tid = threadIdx.x;
    for (int i = tid; i < 384; i += 128) h0[i] = pool[i];
    __syncthreads();
    {
        float s = fb1[tid];
        for (int k = 0; k < 384; k++) s += h0[k] * fw1[k * 128 + tid];
        h1[tid] = fmaxf(s, 0.f);
    }
    __syncthreads();
    if (tid < 64) {
        float s = fb2[tid];
        for (int k = 0; k < 128; k++) s += h1[k] * fw2[k * 64 + tid];
        h2[tid] = fmaxf(s, 0.f);
    }
    __syncthreads();
    if (tid < 10) {
        float s = fb3[tid];
        for (int k = 0; k < 64; k++) s += h2[k] * fw3[k * 10 + tid];
        out[tid] = s;
    }
}

// ---------------- launch ----------------

extern "C" void kernel_launch(void* const* d_in, const int* in_sizes, int n_in,
                              void* d_out, int out_size, void* d_ws, size_t ws_size,
                              hipStream_t stream) {
    const float* x   = (const float*)d_in[0];
    const int*   ei  = (const int*)d_in[1];
    const float* W1  = (const float*)d_in[2];
    const float* b1  = (const float*)d_in[3];
    const float* W2  = (const float*)d_in[4];
    const float* b2  = (const float*)d_in[5];
    const float* W3  = (const float*)d_in[6];
    const float* b3  = (const float*)d_in[7];
    const float* fw1 = (const float*)d_in[8];
    const float* fb1 = (const float*)d_in[9];
    const float* fw2 = (const float*)d_in[10];
    const float* fb2 = (const float*)d_in[11];
    const float* fw3 = (const float*)d_in[12];
    const float* fb3 = (const float*)d_in[13];
    float* out = (float*)d_out;

    const int n  = in_sizes[0] / FDIM;   // 50000
    const int ne = in_sizes[1] / 2;      // 600000
    const int* src = ei;
    const int* tgt = ei + ne;

    char* ws = (char*)d_ws;
    size_t packBytes = (size_t)n * 64 * sizeof(unsigned);   // 12.8 MB
    unsigned* x16  = (unsigned*)ws;  ws += packBytes;
    unsigned* A2   = (unsigned*)ws;  ws += packBytes;
    unsigned* A3   = (unsigned*)ws;  ws += packBytes;
    unsigned short* g8 = (unsigned short*)ws; ws += (((size_t)(n + 1) * 64 * 2 + 15) / 16) * 16; // 6.4 MB
    unsigned* B1t  = (unsigned*)ws;  ws += 128 * 64 * 4;
    unsigned* B2t  = (unsigned*)ws;  ws += 128 * 64 * 4;
    unsigned* B3t  = (unsigned*)ws;  ws += 128 * 64 * 4;
    float* dis  = (float*)ws;        ws += (size_t)n * 4;
    int* count  = (int*)ws;          ws += (size_t)n * 4;
    int* rowptr = (int*)ws;          ws += ((size_t)(n + 4) * 4 / 16) * 16;
    int* cursor = (int*)ws;          ws += (size_t)n * 4;
    int* csrs   = (int*)ws;          ws += (size_t)ne * 4;
    float* pool = (float*)ws;        ws += 384 * 4;
    int nb = (n + 2047) / 2048;      // scan blocks (25)
    int* tpre = (int*)ws;            ws += (size_t)nb * 256 * 4;
    int* bsum = (int*)ws;            ws += ((size_t)(nb + 3) / 4) * 16;
    int* bpre = (int*)ws;            ws += ((size_t)(nb + 3) / 4) * 16;

    // prep (also zeros count before hist; wprep also zeroes g8 row n)
    xprep_kernel<<<(n * 64 + 255) / 256, 256, 0, stream>>>(x, x16, count, n, n * 64);
    wprep_kernel<<<(3 * 8192 + 64 + 255) / 256, 256, 0, stream>>>(W1, W2, W3, B1t, B2t, B3t, g8, n);

    // CSR build
    hist_kernel<<<(ne + 255) / 256, 256, 0, stream>>>(tgt, count, ne);
    scan1_kernel<<<nb, 256, 0, stream>>>(count, dis, tpre, bsum, n);
    scan2_kernel<<<1, 1024, 0, stream>>>(bsum, bpre, rowptr, pool, n, nb);
    scan3_kernel<<<nb, 256, 0, stream>>>(count, tpre, bpre, rowptr, cursor, n);
    fill_kernel<<<(ne + 255) / 256, 256, 0, stream>>>(src, tgt, cursor, csrs, ne);

    int gemmGrid = (n + 63) / 64;
    int aggGrid  = (n + 7) / 8;

    gemm_kernel<<<gemmGrid, 256, 0, stream>>>(x16, B1t, dis, g8, n);
    agg_kernel<<<aggGrid, 512, 0, stream>>>(g8, dis, rowptr, csrs, b1, A2, pool + 0, n);

    gemm_kernel<<<gemmGrid, 256, 0, stream>>>(A2, B2t, dis, g8, n);
    agg_kernel<<<aggGrid, 512, 0, stream>>>(g8, dis, rowptr, csrs, b2, A3, pool + 128, n);

    gemm_kernel<<<gemmGrid, 256, 0, stream>>>(A3, B3t, dis, g8, n);
    agg_kernel<<<aggGrid, 512, 0, stream>>>(g8, dis, rowptr, csrs, b3, (unsigned*)nullptr, pool + 256, n);

    mlp_kernel<<<1, 128, 0, stream>>>(pool, fw1, fb1, fw2, fb2, fw3, fb3, out);
}

// Round 7
// 455.247 us; speedup vs baseline: 1.9149x; 1.9149x over previous
//
#include <hip/hip_runtime.h>

#define FDIM 128

typedef __attribute__((ext_vector_type(8))) short bf16x8;
typedef __attribute__((ext_vector_type(4))) float f32x4;
typedef __attribute__((ext_vector_type(2))) float f32x2;

// ---------------- helpers ----------------

__device__ __forceinline__ unsigned int cvt_bf16(float f) {
    unsigned int u = __float_as_uint(f);
    return (u + 0x7fffu + ((u >> 16) & 1u)) >> 16;   // RNE
}

// bf16 packed layout (GEMM in/out): row of 64 uints; uint u = (feat u, feat u+64).
// fp8 gather layout: row of 64 ushorts (128 B); ushort u = e4m3 pair (feat u, feat u+64),
// value = dis[row] * hw[row][feat]  (pre-scaled by source norm). Row n = zeros.

// ---------------- CSR build ----------------

__global__ void hist_kernel(const int* __restrict__ tgt, int* __restrict__ count, int ne) {
    int e = blockIdx.x * blockDim.x + threadIdx.x;
    if (e < ne) atomicAdd(&count[tgt[e]], 1);
}

// ---- 3-phase parallel scan: 2048 elems/block ----
__global__ __launch_bounds__(256) void scan1_kernel(const int* __restrict__ count,
                                                    float* __restrict__ dis,
                                                    int* __restrict__ tpre,
                                                    int* __restrict__ bsum, int n) {
    __shared__ int sm[256];
    int tid = threadIdx.x, blk = blockIdx.x;
    int base = blk * 2048 + tid * 8;
    int s = 0;
    #pragma unroll
    for (int q = 0; q < 8; q++) {
        int i = base + q;
        if (i < n) {
            int c = count[i];
            s += c;
            dis[i] = rsqrtf((float)(c + 1));   // +1 self-loop
        }
    }
    sm[tid] = s;
    __syncthreads();
    for (int off = 1; off < 256; off <<= 1) {
        int v = sm[tid];
        int u = (tid >= off) ? sm[tid - off] : 0;
        __syncthreads();
        sm[tid] = v + u;
        __syncthreads();
    }
    tpre[blk * 256 + tid] = (tid == 0) ? 0 : sm[tid - 1];
    if (tid == 255) bsum[blk] = sm[255];
}

__global__ __launch_bounds__(1024) void scan2_kernel(const int* __restrict__ bsum,
                                                     int* __restrict__ bpre,
                                                     int* __restrict__ rowptr,
                                                     float* __restrict__ pool,
                                                     int n, int nb) {
    __shared__ int sm[1024];
    int tid = threadIdx.x;
    if (tid < 384) pool[tid] = 0.f;
    sm[tid] = (tid < nb) ? bsum[tid] : 0;
    __syncthreads();
    for (int off = 1; off < 1024; off <<= 1) {
        int v = sm[tid];
        int u = (tid >= off) ? sm[tid - off] : 0;
        __syncthreads();
        sm[tid] = v + u;
        __syncthreads();
    }
    if (tid < nb) bpre[tid] = (tid == 0) ? 0 : sm[tid - 1];
    if (tid == nb - 1) rowptr[n] = sm[tid];
}

__global__ __launch_bounds__(256) void scan3_kernel(const int* __restrict__ count,
                                                    const int* __restrict__ tpre,
                                                    const int* __restrict__ bpre,
                                                    int* __restrict__ rowptr,
                                                    int* __restrict__ cursor, int n) {
    int tid = threadIdx.x, blk = blockIdx.x;
    int run = bpre[blk] + tpre[blk * 256 + tid];
    int base = blk * 2048 + tid * 8;
    #pragma unroll
    for (int q = 0; q < 8; q++) {
        int i = base + q;
        if (i < n) {
            rowptr[i] = run;
            cursor[i] = run;
            run += count[i];
        }
    }
}

__global__ void fill_kernel(const int* __restrict__ src, const int* __restrict__ tgt,
                            int* __restrict__ cursor, int* __restrict__ csrs, int ne) {
    int e = blockIdx.x * blockDim.x + threadIdx.x;
    if (e < ne) {
        int t = tgt[e];
        int s = src[e];
        int slot = atomicAdd(&cursor[t], 1);
        csrs[slot] = s;
    }
}

// ---------------- prep: fp32 -> packed bf16 (+ count zero) ----------------

__global__ void xprep_kernel(const float* __restrict__ x, unsigned* __restrict__ x16,
                             int* __restrict__ count, int n, int total) {
    int i = blockIdx.x * blockDim.x + threadIdx.x;      // total = n*64
    if (i < total) {
        int m = i >> 6, u = i & 63;
        float lo = x[(size_t)m * 128 + u];
        float hi = x[(size_t)m * 128 + u + 64];
        x16[i] = cvt_bf16(lo) | (cvt_bf16(hi) << 16);
        if (i < n) count[i] = 0;
    }
}

__global__ void wprep_kernel(const float* __restrict__ W1, const float* __restrict__ W2,
                             const float* __restrict__ W3,
                             unsigned* __restrict__ B1, unsigned* __restrict__ B2,
                             unsigned* __restrict__ B3,
                             unsigned short* __restrict__ g8, int n) {
    int i = blockIdx.x * blockDim.x + threadIdx.x;      // 3*8192 + 64
    if (i < 3 * 8192) {
        int w = i >> 13;
        int j = i & 8191;
        const float* W = (w == 0) ? W1 : (w == 1) ? W2 : W3;
        unsigned* B    = (w == 0) ? B1 : (w == 1) ? B2 : B3;
        int nn = j >> 6, u = j & 63;
        float lo = W[(size_t)u * 128 + nn];
        float hi = W[(size_t)(u + 64) * 128 + nn];
        B[j] = cvt_bf16(lo) | (cvt_bf16(hi) << 16);
    } else if (i < 3 * 8192 + 64) {
        g8[(size_t)n * 64 + (i - 3 * 8192)] = 0;        // zero row for padded gathers
    }
}

// ---------------- GEMM: g8[n][64u] = fp8(dis[m] * (A16 @ W)) (bf16 MFMA) --------

__global__ __launch_bounds__(256) void gemm_kernel(const unsigned* __restrict__ A16,
                                                   const unsigned* __restrict__ Bt16,
                                                   const float* __restrict__ dis,
                                                   unsigned short* __restrict__ g8, int n) {
    int tid  = threadIdx.x;
    int wave = tid >> 6, lane = tid & 63;
    int quad = lane >> 4, r16 = lane & 15;
    int m0 = (blockIdx.x * 4 + wave) * 16;
    if (m0 >= n) return;

    f32x4 acc[8] = {};

    #pragma unroll
    for (int ks = 0; ks < 4; ks++) {
        int m = m0 + r16;
        if (m >= n) m = n - 1;
        uint4 av = *(const uint4*)(A16 + (size_t)m * 64 + ks * 16 + quad * 4);
        bf16x8 af = *(bf16x8*)&av;
        #pragma unroll
        for (int t = 0; t < 8; t++) {
            int ncol = t * 16 + r16;
            uint4 bv = *(const uint4*)(Bt16 + (size_t)ncol * 64 + ks * 16 + quad * 4);
            bf16x8 bf = *(bf16x8*)&bv;
            acc[t] = __builtin_amdgcn_mfma_f32_16x16x32_bf16(af, bf, acc[t], 0, 0, 0);
        }
    }

    #pragma unroll
    for (int r = 0; r < 4; r++) {
        int row = m0 + quad * 4 + r;
        if (row < n) {
            float dr = dis[row];
            #pragma unroll
            for (int t = 0; t < 4; t++) {
                int p = __builtin_amdgcn_cvt_pk_fp8_f32(dr * acc[t][r], dr * acc[t + 4][r], 0, false);
                g8[(size_t)row * 64 + t * 16 + r16] = (unsigned short)(p & 0xffff);
            }
        }
    }
}

// ---------------- Aggregation: 8 edges per gather instruction ----------------
// wave = (edge-slot j = lane>>3, chunk c = lane&7); lane loads uint4 = 16B = chunk c
// of edge j's fp8 row. Wave handles 4 consecutive nodes (prefetched rowptr/dis/csr).
// Per-node: accumulate per-lane chunk sums, butterfly over j (xor 8/16/32), epilogue.

#define AGG_ACC(v)                                                     \
    { f32x2 p;                                                         \
      p = __builtin_amdgcn_cvt_pk_f32_fp8((int)v.x, 0); f0[0]+=p.x; f1[0]+=p.y; \
      p = __builtin_amdgcn_cvt_pk_f32_fp8((int)v.x, 1); f0[1]+=p.x; f1[1]+=p.y; \
      p = __builtin_amdgcn_cvt_pk_f32_fp8((int)v.y, 0); f0[2]+=p.x; f1[2]+=p.y; \
      p = __builtin_amdgcn_cvt_pk_f32_fp8((int)v.y, 1); f0[3]+=p.x; f1[3]+=p.y; \
      p = __builtin_amdgcn_cvt_pk_f32_fp8((int)v.z, 0); f0[4]+=p.x; f1[4]+=p.y; \
      p = __builtin_amdgcn_cvt_pk_f32_fp8((int)v.z, 1); f0[5]+=p.x; f1[5]+=p.y; \
      p = __builtin_amdgcn_cvt_pk_f32_fp8((int)v.w, 0); f0[6]+=p.x; f1[6]+=p.y; \
      p = __builtin_amdgcn_cvt_pk_f32_fp8((int)v.w, 1); f0[7]+=p.x; f1[7]+=p.y; }

#define AGG_ISSUE(buf, gi)                                             \
    { int e = (gi) * 8 + j;                                            \
      int s = __shfl(ereg, e);                                         \
      if (b + e >= end) s = n;                                         \
      buf = *(const uint4*)(g8 + (size_t)(unsigned)s * 64u + c * 8); }

__global__ __launch_bounds__(512) void agg_kernel(const unsigned short* __restrict__ g8,
                                                  const float* __restrict__ dis,
                                                  const int* __restrict__ rowptr,
                                                  const int* __restrict__ csrs,
                                                  const float* __restrict__ bias,
                                                  unsigned* __restrict__ out16,   // may be null
                                                  float* __restrict__ pool, int n) {
    __shared__ float lpool[128];
    int tid = threadIdx.x;
    if (tid < 128) lpool[tid] = 0.f;
    __syncthreads();

    int wave = tid >> 6, lane = tid & 63;
    int j = lane >> 3;       // edge slot
    int c = lane & 7;        // 16B chunk of the 128B row
    int node0 = (blockIdx.x * 8 + wave) * 4;

    // bias preload (per chunk): features c*8..c*8+7 and +64
    float b0[8], b1[8];
    *(float4*)&b0[0] = *(const float4*)(bias + c * 8);
    *(float4*)&b0[4] = *(const float4*)(bias + c * 8 + 4);
    *(float4*)&b1[0] = *(const float4*)(bias + 64 + c * 8);
    *(float4*)&b1[4] = *(const float4*)(bias + 64 + c * 8 + 4);

    // prefetch rowptr[node0..node0+4] and dis[node0..node0+3]
    int rpv = 0; float dv = 0.f;
    if (lane <= 4) rpv = rowptr[min(node0 + lane, n)];
    if (lane < 4)  dv  = dis[min(node0 + lane, n - 1)];

    // prefetch first 64 edge ids for each of the 4 nodes
    int er[4];
    #pragma unroll
    for (int i = 0; i < 4; i++) {
        int beg = __shfl(rpv, i);
        er[i] = csrs[beg + lane];          // csrs padded by 64 entries
    }

    float pp0[8] = {}, pp1[8] = {};

    #pragma unroll
    for (int i = 0; i < 4; i++) {
        int node = node0 + i;
        if (node >= n) break;
        int beg = __shfl(rpv, i);
        int end = __shfl(rpv, i + 1);
        float di = __shfl(dv, i);

        float f0[8] = {}, f1[8] = {};
        // self row (lanes j==0 read node's row; others hit the zero row)
        {
            int s = (j == 0) ? node : n;
            uint4 sv = *(const uint4*)(g8 + (size_t)(unsigned)s * 64u + c * 8);
            AGG_ACC(sv)
        }
        int ereg = er[i];
        for (int b = beg; b < end; b += 64) {
            if (b != beg) ereg = csrs[b + lane];   // deg>64 only (rare)
            int m = min(64, end - b);
            int ng = (m + 7) >> 3;
            uint4 gv0, gv1;
            AGG_ISSUE(gv0, 0)
            int gi = 0;
            while (true) {
                if (gi + 1 < ng) AGG_ISSUE(gv1, gi + 1)
                AGG_ACC(gv0)
                gi++;
                if (gi >= ng) break;
                if (gi + 1 < ng) AGG_ISSUE(gv0, gi + 1)
                AGG_ACC(gv1)
                gi++;
                if (gi >= ng) break;
            }
        }

        // butterfly reduce over edge-slot lanes (j): xor 8,16,32
        #pragma unroll
        for (int k = 0; k < 8; k++) {
            f0[k] += __shfl_xor(f0[k], 8);  f1[k] += __shfl_xor(f1[k], 8);
            f0[k] += __shfl_xor(f0[k], 16); f1[k] += __shfl_xor(f1[k], 16);
            f0[k] += __shfl_xor(f0[k], 32); f1[k] += __shfl_xor(f1[k], 32);
        }

        // epilogue: scale by dis[t], bias, relu; store bf16-packed row; pool
        float r0[8], r1[8];
        #pragma unroll
        for (int k = 0; k < 8; k++) {
            r0[k] = fmaxf(di * f0[k] + b0[k], 0.f);
            r1[k] = fmaxf(di * f1[k] + b1[k], 0.f);
            pp0[k] += r0[k];
            pp1[k] += r1[k];
        }
        if (out16 && j == 0) {
            uint4 wa, wb;
            wa.x = cvt_bf16(r0[0]) | (cvt_bf16(r1[0]) << 16);
            wa.y = cvt_bf16(r0[1]) | (cvt_bf16(r1[1]) << 16);
            wa.z = cvt_bf16(r0[2]) | (cvt_bf16(r1[2]) << 16);
            wa.w = cvt_bf16(r0[3]) | (cvt_bf16(r1[3]) << 16);
            wb.x = cvt_bf16(r0[4]) | (cvt_bf16(r1[4]) << 16);
            wb.y = cvt_bf16(r0[5]) | (cvt_bf16(r1[5]) << 16);
            wb.z = cvt_bf16(r0[6]) | (cvt_bf16(r1[6]) << 16);
            wb.w = cvt_bf16(r0[7]) | (cvt_bf16(r1[7]) << 16);
            *(uint4*)(out16 + (size_t)node * 64 + c * 8)     = wa;
            *(uint4*)(out16 + (size_t)node * 64 + c * 8 + 4) = wb;
        }
    }

    // pool: pp values are post-butterfly (identical across j); add once
    if (j == 0) {
        #pragma unroll
        for (int k = 0; k < 8; k++) {
            atomicAdd(&lpool[c * 8 + k],      pp0[k]);
            atomicAdd(&lpool[64 + c * 8 + k], pp1[k]);
        }
    }
    __syncthreads();
    if (tid < 128) atomicAdd(&pool[tid], lpool[tid]);
}

// ---------------- MLP head (single block) ----------------

__global__ __launch_bounds__(128) void mlp_kernel(const float* __restrict__ pool,
                                                  const float* __restrict__ fw1, const float* __restrict__ fb1,
                                                  const float* __restrict__ fw2, const float* __restrict__ fb2,
                                                  const float* __restrict__ fw3, const float* __restrict__ fb3,
                                                  float* __restrict__ out) {
    __shared__ float h0[384];
    __shared__ float h1[128];
    __shared__ float h2[64];
    int tid = threadIdx.x;
    for (int i = tid; i < 384; i += 128) h0[i] = pool[i];
    __syncthreads();
    {
        float s = fb1[tid];
        for (int k = 0; k < 384; k++) s += h0[k] * fw1[k * 128 + tid];
        h1[tid] = fmaxf(s, 0.f);
    }
    __syncthreads();
    if (tid < 64) {
        float s = fb2[tid];
        for (int k = 0; k < 128; k++) s += h1[k] * fw2[k * 64 + tid];
        h2[tid] = fmaxf(s, 0.f);
    }
    __syncthreads();
    if (tid < 10) {
        float s = fb3[tid];
        for (int k = 0; k < 64; k++) s += h2[k] * fw3[k * 10 + tid];
        out[tid] = s;
    }
}

// ---------------- launch ----------------

extern "C" void kernel_launch(void* const* d_in, const int* in_sizes, int n_in,
                              void* d_out, int out_size, void* d_ws, size_t ws_size,
                              hipStream_t stream) {
    const float* x   = (const float*)d_in[0];
    const int*   ei  = (const int*)d_in[1];
    const float* W1  = (const float*)d_in[2];
    const float* b1  = (const float*)d_in[3];
    const float* W2  = (const float*)d_in[4];
    const float* b2  = (const float*)d_in[5];
    const float* W3  = (const float*)d_in[6];
    const float* b3  = (const float*)d_in[7];
    const float* fw1 = (const float*)d_in[8];
    const float* fb1 = (const float*)d_in[9];
    const float* fw2 = (const float*)d_in[10];
    const float* fb2 = (const float*)d_in[11];
    const float* fw3 = (const float*)d_in[12];
    const float* fb3 = (const float*)d_in[13];
    float* out = (float*)d_out;

    const int n  = in_sizes[0] / FDIM;   // 50000
    const int ne = in_sizes[1] / 2;      // 600000
    const int* src = ei;
    const int* tgt = ei + ne;

    char* ws = (char*)d_ws;
    size_t packBytes = (size_t)n * 64 * sizeof(unsigned);   // 12.8 MB
    unsigned* x16  = (unsigned*)ws;  ws += packBytes;
    unsigned* A2   = (unsigned*)ws;  ws += packBytes;
    unsigned* A3   = (unsigned*)ws;  ws += packBytes;
    unsigned short* g8 = (unsigned short*)ws; ws += (((size_t)(n + 1) * 64 * 2 + 127) / 128) * 128; // 6.4 MB
    unsigned* B1t  = (unsigned*)ws;  ws += 128 * 64 * 4;
    unsigned* B2t  = (unsigned*)ws;  ws += 128 * 64 * 4;
    unsigned* B3t  = (unsigned*)ws;  ws += 128 * 64 * 4;
    float* dis  = (float*)ws;        ws += (size_t)n * 4;
    int* count  = (int*)ws;          ws += (size_t)n * 4;
    int* rowptr = (int*)ws;          ws += ((size_t)(n + 4) * 4 / 16) * 16;
    int* cursor = (int*)ws;          ws += (size_t)n * 4;
    int* csrs   = (int*)ws;          ws += (size_t)(ne + 64) * 4;   // +64 pad for prefetch
    float* pool = (float*)ws;        ws += 384 * 4;
    int nb = (n + 2047) / 2048;      // scan blocks (25)
    int* tpre = (int*)ws;            ws += (size_t)nb * 256 * 4;
    int* bsum = (int*)ws;            ws += ((size_t)(nb + 3) / 4) * 16;
    int* bpre = (int*)ws;            ws += ((size_t)(nb + 3) / 4) * 16;

    // prep (also zeros count before hist; wprep also zeroes g8 row n)
    xprep_kernel<<<(n * 64 + 255) / 256, 256, 0, stream>>>(x, x16, count, n, n * 64);
    wprep_kernel<<<(3 * 8192 + 64 + 255) / 256, 256, 0, stream>>>(W1, W2, W3, B1t, B2t, B3t, g8, n);

    // CSR build
    hist_kernel<<<(ne + 255) / 256, 256, 0, stream>>>(tgt, count, ne);
    scan1_kernel<<<nb, 256, 0, stream>>>(count, dis, tpre, bsum, n);
    scan2_kernel<<<1, 1024, 0, stream>>>(bsum, bpre, rowptr, pool, n, nb);
    scan3_kernel<<<nb, 256, 0, stream>>>(count, tpre, bpre, rowptr, cursor, n);
    fill_kernel<<<(ne + 255) / 256, 256, 0, stream>>>(src, tgt, cursor, csrs, ne);

    int gemmGrid = (n + 63) / 64;
    int aggGrid  = (n + 31) / 32;    // 8 waves x 4 nodes per block

    gemm_kernel<<<gemmGrid, 256, 0, stream>>>(x16, B1t, dis, g8, n);
    agg_kernel<<<aggGrid, 512, 0, stream>>>(g8, dis, rowptr, csrs, b1, A2, pool + 0, n);

    gemm_kernel<<<gemmGrid, 256, 0, stream>>>(A2, B2t, dis, g8, n);
    agg_kernel<<<aggGrid, 512, 0, stream>>>(g8, dis, rowptr, csrs, b2, A3, pool + 128, n);

    gemm_kernel<<<gemmGrid, 256, 0, stream>>>(A3, B3t, dis, g8, n);
    agg_kernel<<<aggGrid, 512, 0, stream>>>(g8, dis, rowptr, csrs, b3, (unsigned*)nullptr, pool + 256, n);

    mlp_kernel<<<1, 128, 0, stream>>>(pool, fw1, fb1, fw2, fb2, fw3, fb3, out);
}